// Round 12
// baseline (264.186 us; speedup 1.0000x reference)
//
#include <hip/hip_runtime.h>
#include <hip/hip_bf16.h>

typedef float f32x16 __attribute__((ext_vector_type(16)));
typedef int   i32x8  __attribute__((ext_vector_type(8)));
typedef int   i32x4  __attribute__((ext_vector_type(4)));

#define FP8_MAX 448.0f

// ---------------- helpers ----------------

__device__ __forceinline__ void g2l16(const void* g, void* l) {
    __builtin_amdgcn_global_load_lds(
        (const __attribute__((address_space(1))) void*)g,
        (__attribute__((address_space(3))) void*)l,
        16, 0, 0);
}

__device__ __forceinline__ float scale_from(float amax) {
    float s = FP8_MAX / (amax * 1.1f);
    return (amax == 0.0f) ? 1.0f : fminf(s, 10000.0f);
}

// ---------------- preprocessing (unchanged; at its BW roofline) ----------------

__global__ void init_kernel(unsigned* amax) {
    amax[0] = 0u;
    amax[1] = 0u;
}

__global__ void amax_fused_kernel(const float* __restrict__ x, size_t nx,
                                  const float* __restrict__ w, size_t nw,
                                  unsigned* __restrict__ amax, int xblocks) {
    const float* src;
    size_t n;
    unsigned* out;
    int bid, nb;
    if ((int)blockIdx.x < xblocks) {
        src = x; n = nx; out = amax; bid = blockIdx.x; nb = xblocks;
    } else {
        src = w; n = nw; out = amax + 1; bid = blockIdx.x - xblocks; nb = gridDim.x - xblocks;
    }
    float m = 0.0f;
    const size_t ustep = (size_t)blockDim.x * 4;
    const size_t chunkf = ustep * 8;
    size_t base = (size_t)bid * chunkf + (size_t)threadIdx.x * 4;
    const size_t gstride = (size_t)nb * chunkf;
    for (; base < n; base += gstride) {
        float4 v[8];
        #pragma unroll
        for (int u = 0; u < 8; ++u) {
            size_t idx = base + (size_t)u * ustep;
            float4 vv = {0.0f, 0.0f, 0.0f, 0.0f};
            if (idx < n) vv = *(const float4*)(src + idx);
            v[u] = vv;
        }
        #pragma unroll
        for (int u = 0; u < 8; ++u)
            m = fmaxf(m, fmaxf(fmaxf(fabsf(v[u].x), fabsf(v[u].y)),
                               fmaxf(fabsf(v[u].z), fabsf(v[u].w))));
    }
    #pragma unroll
    for (int off = 32; off > 0; off >>= 1)
        m = fmaxf(m, __shfl_xor(m, off));
    __shared__ float sm[4];
    if ((threadIdx.x & 63) == 0) sm[threadIdx.x >> 6] = m;
    __syncthreads();
    if (threadIdx.x == 0) {
        float mm = fmaxf(fmaxf(sm[0], sm[1]), fmaxf(sm[2], sm[3]));
        atomicMax(out, __float_as_uint(mm));   // non-negative: uint order == float order
    }
}

__device__ __forceinline__ float qclamp(float v, float s) {
    return fminf(fmaxf(v * s, -FP8_MAX), FP8_MAX);
}

__global__ void quant_fused_kernel(const float* __restrict__ x, size_t nx,
                                   const float* __restrict__ w, size_t nw,
                                   const unsigned* __restrict__ amax,
                                   unsigned char* __restrict__ xq,
                                   unsigned char* __restrict__ wq, int xblocks) {
    const float* src;
    size_t n;
    unsigned char* dst;
    int bid, nb, sel;
    if ((int)blockIdx.x < xblocks) {
        src = x; n = nx; dst = xq; bid = blockIdx.x; nb = xblocks; sel = 0;
    } else {
        src = w; n = nw; dst = wq; bid = blockIdx.x - xblocks; nb = gridDim.x - xblocks; sel = 1;
    }
    const float s = scale_from(__uint_as_float(amax[sel]));
    const size_t ustep = (size_t)blockDim.x * 4;
    const size_t chunkf = ustep * 4;
    size_t base = (size_t)bid * chunkf + (size_t)threadIdx.x * 4;
    const size_t gstride = (size_t)nb * chunkf;
    for (; base < n; base += gstride) {
        float4 v[4];
        bool ok[4];
        #pragma unroll
        for (int u = 0; u < 4; ++u) {
            size_t idx = base + (size_t)u * ustep;
            ok[u] = idx < n;
            float4 vv = {0.0f, 0.0f, 0.0f, 0.0f};
            if (ok[u]) vv = *(const float4*)(src + idx);
            v[u] = vv;
        }
        #pragma unroll
        for (int u = 0; u < 4; ++u) {
            if (ok[u]) {
                int p = __builtin_amdgcn_cvt_pk_fp8_f32(qclamp(v[u].x, s), qclamp(v[u].y, s), 0, false);
                p = __builtin_amdgcn_cvt_pk_fp8_f32(qclamp(v[u].z, s), qclamp(v[u].w, s), p, true);
                *(unsigned*)(dst + base + (size_t)u * ustep) = (unsigned)p;
            }
        }
    }
}

// ---------------- GEMM: r3 structure + A operand global->register hybrid ------------
// r3 (140us, MfmaUtil 43%): MFMA-busy time == compute ideal; the other 57% is
// the staging/barrier window. This round SHRINKS the window's work instead of
// reordering it (5x falsified): A fragments are per-wave contiguous 32B
// row-chunks -> load straight to VGPRs alongside the B staging; they complete
// inside the same vmcnt(0) drain the barrier already does. Staging issues
// 12->8 g2l16, LDS 48->32KB, ds_reads 24->16 per lane/iter (A's removed ->
// conflicts -1/3). HBM bytes unchanged (A dup across 2 row-partner waves = L1
// hit). B path, swizzle, MFMA, epilogue bit-identical to r3.
#define BM 128
#define BN 256
#define BKB 128

__global__ __launch_bounds__(256, 2) void gemm_fp8_kernel(
    const unsigned char* __restrict__ Aq,
    const unsigned char* __restrict__ Bq,
    const float* __restrict__ bias,
    const unsigned* __restrict__ amax,
    float* __restrict__ out,
    int M, int N, int K) {
    __shared__ alignas(16) unsigned char sB[BN * BKB];   // 32 KB (B only)

    const int tid = threadIdx.x;
    const int wave = tid >> 6;
    const int lane = tid & 63;
    const int nbn = N / BN;
    const int brow = (blockIdx.x / nbn) * BM;
    const int bcol = (blockIdx.x % nbn) * BN;
    const int wrow = (wave >> 1) * 64;
    const int wcol = (wave & 1) * 128;

    f32x16 acc[2][4] = {};

    const int r31 = lane & 31;
    const int half = lane >> 5;
    const int so = tid * 16;

    union AB { i32x8 v8; i32x4 v4[2]; };

    // per-lane A fragment base addresses (row fixed across K-loop)
    const size_t sK = (size_t)K;
    const unsigned char* ap[2];
    #pragma unroll
    for (int m = 0; m < 2; ++m)
        ap[m] = Aq + (size_t)(brow + wrow + m * 32 + r31) * sK + half * 32;

    for (int k0 = 0; k0 < K; k0 += BKB) {
        __syncthreads();   // previous compute done reading LDS
        // stage B to LDS (8 issues)
        #pragma unroll
        for (int i = 0; i < 8; ++i) {
            int oo = i * 4096 + so;
            int r = oo >> 7;
            int cl = (oo & 127) ^ ((r & 7) << 4);
            g2l16(Bq + (size_t)(bcol + r) * K + k0 + cl, &sB[i * 4096 + wave * 1024]);
        }
        // load A fragments (both ks) straight to registers; same drain window
        AB a[2][2];
        #pragma unroll
        for (int m = 0; m < 2; ++m)
            #pragma unroll
            for (int ks = 0; ks < 2; ++ks) {
                const unsigned char* p = ap[m] + k0 + ks * 64;
                a[m][ks].v4[0] = *(const i32x4*)(p);
                a[m][ks].v4[1] = *(const i32x4*)(p + 16);
            }
        __syncthreads();   // compiler drains vmcnt(0): B in LDS, A in regs

        #pragma unroll
        for (int ks = 0; ks < 2; ++ks) {
            const int kb = ks * 64 + half * 32;
            AB b[4];
            #pragma unroll
            for (int n = 0; n < 4; ++n) {
                int row = wcol + n * 32 + r31;
                int bse = row * BKB;
                int sw = (row & 7) << 4;
                b[n].v4[0] = *(const i32x4*)&sB[bse + (kb ^ sw)];
                b[n].v4[1] = *(const i32x4*)&sB[bse + ((kb + 16) ^ sw)];
            }
            #pragma unroll
            for (int m = 0; m < 2; ++m)
                #pragma unroll
                for (int n = 0; n < 4; ++n)
                    acc[m][n] = __builtin_amdgcn_mfma_scale_f32_32x32x64_f8f6f4(
                        a[m][ks].v8, b[n].v8, acc[m][n],
                        0, 0, 0, 0x7f7f7f7f, 0, 0x7f7f7f7f);
        }
    }

    // epilogue: 32x32 C/D layout: col = lane&31, row = (reg&3) + 8*(reg>>2) + 4*(lane>>5)
    const float invx = 1.0f / scale_from(__uint_as_float(amax[0]));
    const float invw = 1.0f / scale_from(__uint_as_float(amax[1]));
    const float s2 = invx * invw;
    #pragma unroll
    for (int n = 0; n < 4; ++n) {
        int col = bcol + wcol + n * 32 + r31;
        float bv = bias[col];
        #pragma unroll
        for (int m = 0; m < 2; ++m) {
            int rbase = brow + wrow + m * 32 + half * 4;
            #pragma unroll
            for (int r = 0; r < 16; ++r) {
                int row = rbase + (r & 3) + 8 * (r >> 2);
                out[(size_t)row * N + col] = acc[m][n][r] * s2 + bv;
            }
        }
    }
}

// ---------------- launch ----------------

extern "C" void kernel_launch(void* const* d_in, const int* in_sizes, int n_in,
                              void* d_out, int out_size, void* d_ws, size_t ws_size,
                              hipStream_t stream) {
    const float* x    = (const float*)d_in[0];
    const float* w    = (const float*)d_in[1];
    const float* bias = (const float*)d_in[2];
    float* out = (float*)d_out;

    const size_t nx = (size_t)in_sizes[0];
    const size_t nw = (size_t)in_sizes[1];
    const int N = in_sizes[2];
    const int K = (int)(nw / (size_t)N);
    const int M = (int)(nx / (size_t)K);

    unsigned* amax = (unsigned*)d_ws;
    unsigned char* xq = (unsigned char*)d_ws + 256;
    unsigned char* wq = xq + nx;

    const int TOTB = 2048;
    int xb = (int)((double)TOTB * (double)nx / (double)(nx + nw));
    if (xb < 1) xb = 1;
    if (xb > TOTB - 1) xb = TOTB - 1;

    init_kernel<<<1, 1, 0, stream>>>(amax);
    amax_fused_kernel<<<TOTB, 256, 0, stream>>>(x, nx, w, nw, amax, xb);
    quant_fused_kernel<<<TOTB, 256, 0, stream>>>(x, nx, w, nw, amax, xq, wq, xb);

    dim3 grid((M / BM) * (N / BN));
    gemm_fp8_kernel<<<grid, 256, 0, stream>>>(xq, wq, bias, amax, out, M, N, K);
}

// Round 13
// 216.259 us; speedup vs baseline: 1.2216x; 1.2216x over previous
//
#include <hip/hip_runtime.h>
#include <hip/hip_bf16.h>

typedef float f32x16 __attribute__((ext_vector_type(16)));
typedef int   i32x8  __attribute__((ext_vector_type(8)));
typedef int   i32x4  __attribute__((ext_vector_type(4)));

#define FP8_MAX 448.0f

// ---------------- helpers ----------------

__device__ __forceinline__ void g2l16(const void* g, void* l) {
    __builtin_amdgcn_global_load_lds(
        (const __attribute__((address_space(1))) void*)g,
        (__attribute__((address_space(3))) void*)l,
        16, 0, 0);
}

__device__ __forceinline__ float scale_from(float amax) {
    float s = FP8_MAX / (amax * 1.1f);
    return (amax == 0.0f) ? 1.0f : fminf(s, 10000.0f);
}

// ---------------- preprocessing (at its BW roofline) ----------------

__global__ void init_kernel(unsigned* amax) {
    amax[0] = 0u;
    amax[1] = 0u;
}

__global__ void amax_fused_kernel(const float* __restrict__ x, size_t nx,
                                  const float* __restrict__ w, size_t nw,
                                  unsigned* __restrict__ amax, int xblocks) {
    const float* src;
    size_t n;
    unsigned* out;
    int bid, nb;
    if ((int)blockIdx.x < xblocks) {
        src = x; n = nx; out = amax; bid = blockIdx.x; nb = xblocks;
    } else {
        src = w; n = nw; out = amax + 1; bid = blockIdx.x - xblocks; nb = gridDim.x - xblocks;
    }
    float m = 0.0f;
    const size_t ustep = (size_t)blockDim.x * 4;
    const size_t chunkf = ustep * 8;
    size_t base = (size_t)bid * chunkf + (size_t)threadIdx.x * 4;
    const size_t gstride = (size_t)nb * chunkf;
    for (; base < n; base += gstride) {
        float4 v[8];
        #pragma unroll
        for (int u = 0; u < 8; ++u) {
            size_t idx = base + (size_t)u * ustep;
            float4 vv = {0.0f, 0.0f, 0.0f, 0.0f};
            if (idx < n) vv = *(const float4*)(src + idx);
            v[u] = vv;
        }
        #pragma unroll
        for (int u = 0; u < 8; ++u)
            m = fmaxf(m, fmaxf(fmaxf(fabsf(v[u].x), fabsf(v[u].y)),
                               fmaxf(fabsf(v[u].z), fabsf(v[u].w))));
    }
    #pragma unroll
    for (int off = 32; off > 0; off >>= 1)
        m = fmaxf(m, __shfl_xor(m, off));
    __shared__ float sm[4];
    if ((threadIdx.x & 63) == 0) sm[threadIdx.x >> 6] = m;
    __syncthreads();
    if (threadIdx.x == 0) {
        float mm = fmaxf(fmaxf(sm[0], sm[1]), fmaxf(sm[2], sm[3]));
        atomicMax(out, __float_as_uint(mm));   // non-negative: uint order == float order
    }
}

__device__ __forceinline__ float qclamp(float v, float s) {
    return fminf(fmaxf(v * s, -FP8_MAX), FP8_MAX);
}

__global__ void quant_fused_kernel(const float* __restrict__ x, size_t nx,
                                   const float* __restrict__ w, size_t nw,
                                   const unsigned* __restrict__ amax,
                                   unsigned char* __restrict__ xq,
                                   unsigned char* __restrict__ wq, int xblocks) {
    const float* src;
    size_t n;
    unsigned char* dst;
    int bid, nb, sel;
    if ((int)blockIdx.x < xblocks) {
        src = x; n = nx; dst = xq; bid = blockIdx.x; nb = xblocks; sel = 0;
    } else {
        src = w; n = nw; dst = wq; bid = blockIdx.x - xblocks; nb = gridDim.x - xblocks; sel = 1;
    }
    const float s = scale_from(__uint_as_float(amax[sel]));
    const size_t ustep = (size_t)blockDim.x * 4;
    const size_t chunkf = ustep * 4;
    size_t base = (size_t)bid * chunkf + (size_t)threadIdx.x * 4;
    const size_t gstride = (size_t)nb * chunkf;
    for (; base < n; base += gstride) {
        float4 v[4];
        bool ok[4];
        #pragma unroll
        for (int u = 0; u < 4; ++u) {
            size_t idx = base + (size_t)u * ustep;
            ok[u] = idx < n;
            float4 vv = {0.0f, 0.0f, 0.0f, 0.0f};
            if (ok[u]) vv = *(const float4*)(src + idx);
            v[u] = vv;
        }
        #pragma unroll
        for (int u = 0; u < 4; ++u) {
            if (ok[u]) {
                int p = __builtin_amdgcn_cvt_pk_fp8_f32(qclamp(v[u].x, s), qclamp(v[u].y, s), 0, false);
                p = __builtin_amdgcn_cvt_pk_fp8_f32(qclamp(v[u].z, s), qclamp(v[u].w, s), p, true);
                *(unsigned*)(dst + base + (size_t)u * ustep) = (unsigned)p;
            }
        }
    }
}

// ---------------- GEMM (round-3 artifact: measured optimum of this search) ----------
// out[m][n] = (sum_k xq[m][k]*wq[n][k]) * invx * invw + bias[n]
// Block tile 128x256, BK=128B; 4 waves 2x2; wave tile 64x128 = 2x4 frags 32x32.
// mfma_scale_f32_32x32x64_f8f6f4 with unit scales (e8m0 0x7F=1.0): identical
// math to plain fp8 at 2.27x the rate. Single-buffer LDS + 2-barrier drain;
// 48KB LDS + ~116 VGPR -> 3 blocks/CU of TLP. Rounds 4-12 falsified: 8-phase
// (176us), ring-4 (165), reg-dbuf (155), 2-block ring-3 (177), flatmm (387),
// 128^2 tile (145), A-reg hybrid (202) — vs this kernel's 140us / MfmaUtil 43%.
#define BM 128
#define BN 256
#define BKB 128

__global__ __launch_bounds__(256, 2) void gemm_fp8_kernel(
    const unsigned char* __restrict__ Aq,
    const unsigned char* __restrict__ Bq,
    const float* __restrict__ bias,
    const unsigned* __restrict__ amax,
    float* __restrict__ out,
    int M, int N, int K) {
    __shared__ alignas(16) unsigned char sA[BM * BKB];
    __shared__ alignas(16) unsigned char sB[BN * BKB];

    const int tid = threadIdx.x;
    const int wave = tid >> 6;
    const int lane = tid & 63;
    const int nbn = N / BN;
    const int brow = (blockIdx.x / nbn) * BM;
    const int bcol = (blockIdx.x % nbn) * BN;
    const int wrow = (wave >> 1) * 64;
    const int wcol = (wave & 1) * 128;

    f32x16 acc[2][4] = {};

    const int r31 = lane & 31;
    const int half = lane >> 5;
    const int so = tid * 16;

    union AB { i32x8 v8; i32x4 v4[2]; };

    for (int k0 = 0; k0 < K; k0 += BKB) {
        __syncthreads();
        #pragma unroll
        for (int i = 0; i < 4; ++i) {
            int oo = i * 4096 + so;
            int r = oo >> 7;
            int cl = (oo & 127) ^ ((r & 7) << 4);
            g2l16(Aq + (size_t)(brow + r) * K + k0 + cl, &sA[i * 4096 + wave * 1024]);
        }
        #pragma unroll
        for (int i = 0; i < 8; ++i) {
            int oo = i * 4096 + so;
            int r = oo >> 7;
            int cl = (oo & 127) ^ ((r & 7) << 4);
            g2l16(Bq + (size_t)(bcol + r) * K + k0 + cl, &sB[i * 4096 + wave * 1024]);
        }
        __syncthreads();

        #pragma unroll
        for (int ks = 0; ks < 2; ++ks) {
            const int kb = ks * 64 + half * 32;
            AB a[2], b[4];
            #pragma unroll
            for (int m = 0; m < 2; ++m) {
                int row = wrow + m * 32 + r31;
                int bse = row * BKB;
                int sw = (row & 7) << 4;
                a[m].v4[0] = *(const i32x4*)&sA[bse + (kb ^ sw)];
                a[m].v4[1] = *(const i32x4*)&sA[bse + ((kb + 16) ^ sw)];
            }
            #pragma unroll
            for (int n = 0; n < 4; ++n) {
                int row = wcol + n * 32 + r31;
                int bse = row * BKB;
                int sw = (row & 7) << 4;
                b[n].v4[0] = *(const i32x4*)&sB[bse + (kb ^ sw)];
                b[n].v4[1] = *(const i32x4*)&sB[bse + ((kb + 16) ^ sw)];
            }
            #pragma unroll
            for (int m = 0; m < 2; ++m)
                #pragma unroll
                for (int n = 0; n < 4; ++n)
                    acc[m][n] = __builtin_amdgcn_mfma_scale_f32_32x32x64_f8f6f4(
                        a[m].v8, b[n].v8, acc[m][n],
                        0, 0, 0, 0x7f7f7f7f, 0, 0x7f7f7f7f);
        }
    }

    const float invx = 1.0f / scale_from(__uint_as_float(amax[0]));
    const float invw = 1.0f / scale_from(__uint_as_float(amax[1]));
    #pragma unroll
    for (int n = 0; n < 4; ++n) {
        int col = bcol + wcol + n * 32 + r31;
        float bv = bias[col];
        #pragma unroll
        for (int m = 0; m < 2; ++m) {
            int rbase = brow + wrow + m * 32 + half * 4;
            #pragma unroll
            for (int r = 0; r < 16; ++r) {
                int row = rbase + (r & 3) + 8 * (r >> 2);
                out[(size_t)row * N + col] = acc[m][n][r] * invx * invw + bv;
            }
        }
    }
}

// ---------------- launch ----------------

extern "C" void kernel_launch(void* const* d_in, const int* in_sizes, int n_in,
                              void* d_out, int out_size, void* d_ws, size_t ws_size,
                              hipStream_t stream) {
    const float* x    = (const float*)d_in[0];
    const float* w    = (const float*)d_in[1];
    const float* bias = (const float*)d_in[2];
    float* out = (float*)d_out;

    const size_t nx = (size_t)in_sizes[0];
    const size_t nw = (size_t)in_sizes[1];
    const int N = in_sizes[2];
    const int K = (int)(nw / (size_t)N);
    const int M = (int)(nx / (size_t)K);

    unsigned* amax = (unsigned*)d_ws;
    unsigned char* xq = (unsigned char*)d_ws + 256;
    unsigned char* wq = xq + nx;

    const int TOTB = 2048;
    int xb = (int)((double)TOTB * (double)nx / (double)(nx + nw));
    if (xb < 1) xb = 1;
    if (xb > TOTB - 1) xb = TOTB - 1;

    init_kernel<<<1, 1, 0, stream>>>(amax);
    amax_fused_kernel<<<TOTB, 256, 0, stream>>>(x, nx, w, nw, amax, xb);
    quant_fused_kernel<<<TOTB, 256, 0, stream>>>(x, nx, w, nw, amax, xq, wq, xb);

    dim3 grid((M / BM) * (N / BN));
    gemm_fp8_kernel<<<grid, 256, 0, stream>>>(xq, wq, bias, amax, out, M, N, K);
}